// Round 2
// baseline (752.752 us; speedup 1.0000x reference)
//
#include <hip/hip_runtime.h>
#include <hip/hip_bf16.h>

#define B_N 8192
#define K_N 16
#define D_N 1024
#define C_N 512
#define BM  32
#define CONVW_BLOCKS 4096
#define SCATTER_BLOCKS 32

typedef __bf16 bf16x8 __attribute__((ext_vector_type(8)));
typedef __bf16 bf16x2 __attribute__((ext_vector_type(2)));
typedef float  f32x4  __attribute__((ext_vector_type(4)));
typedef float  f32x4v __attribute__((ext_vector_type(4)));
typedef unsigned int u32x4 __attribute__((ext_vector_type(4)));

static __device__ __forceinline__ unsigned short f2bf(float f) {
    union { float f; unsigned int u; } x; x.f = f;
    unsigned int r = x.u + 0x7FFFu + ((x.u >> 16) & 1u);   // RNE
    return (unsigned short)(r >> 16);
}

static __device__ __forceinline__ bf16x2 pk2(float x, float y) {
#if __has_builtin(__builtin_amdgcn_cvt_pk_bf16_f32)
    return __builtin_amdgcn_cvt_pk_bf16_f32(x, y);
#else
    union { unsigned int u; bf16x2 v; } t;
    t.u = (unsigned)f2bf(x) | ((unsigned)f2bf(y) << 16);
    return t.v;
#endif
}

static __device__ __forceinline__ bf16x8 cvt8(f32x4v a, f32x4v b) {
    bf16x2 p0 = pk2(a[0], a[1]), p1 = pk2(a[2], a[3]);
    bf16x2 p2 = pk2(b[0], b[1]), p3 = pk2(b[2], b[3]);
    bf16x8 r;
    r[0] = p0[0]; r[1] = p0[1]; r[2] = p1[0]; r[3] = p1[1];
    r[4] = p2[0]; r[5] = p2[1]; r[6] = p3[0]; r[7] = p3[1];
    return r;
}

static __device__ __forceinline__ bf16x8 load_bf8(const unsigned short* p) {
    union { u32x4 u; bf16x8 v; } t;
    t.u = *(const u32x4*)p;
    return t.v;
}

// ---- setup: histogram + offsets + cursor/ce init, one block ----
__global__ void histk(const int* __restrict__ slot_ids, int* __restrict__ counts,
                      int* __restrict__ offsets, int* __restrict__ cursors,
                      float* __restrict__ ce_sums) {
    __shared__ int h[K_N];
    int t = threadIdx.x;
    if (t < K_N) h[t] = 0;
    __syncthreads();
    for (int b = t; b < B_N; b += 1024) atomicAdd(&h[slot_ids[b]], 1);
    __syncthreads();
    if (t == 0) {
        int a = 0;
        for (int s = 0; s < K_N; ++s) {
            int c = h[s];
            counts[s] = c; offsets[s] = a; cursors[s] = a; ce_sums[s] = 0.f;
            a += c;
        }
    }
}

// ---- fused: W fp32->bf16 convert (blocks [0,4096)) + scatter (blocks [4096,4128)) ----
__global__ void prep(const float* __restrict__ W, unsigned short* __restrict__ Wb,
                     const int* __restrict__ slot_ids, const int* __restrict__ labels,
                     int* __restrict__ cursors, int* __restrict__ order_rows,
                     int* __restrict__ lab_g) {
    int bid = blockIdx.x;
    if (bid < CONVW_BLOCKS) {
        size_t i = ((size_t)bid * 256 + threadIdx.x) * 8;
        f32x4v a = *(const f32x4v*)(W + i);
        f32x4v b = *(const f32x4v*)(W + i + 4);
        u32x4 o;
        o[0] = (unsigned)f2bf(a[0]) | ((unsigned)f2bf(a[1]) << 16);
        o[1] = (unsigned)f2bf(a[2]) | ((unsigned)f2bf(a[3]) << 16);
        o[2] = (unsigned)f2bf(b[0]) | ((unsigned)f2bf(b[1]) << 16);
        o[3] = (unsigned)f2bf(b[2]) | ((unsigned)f2bf(b[3]) << 16);
        *(u32x4*)(Wb + i) = o;
    } else {
        int b0 = bid - CONVW_BLOCKS;
        for (int b = b0 * 256 + threadIdx.x; b < B_N; b += SCATTER_BLOCKS * 256) {
            int s = slot_ids[b];
            int idx = atomicAdd(&cursors[s], 1);
            order_rows[idx] = b * K_N + s;   // flat row into concepts (b,s,:)
            lab_g[idx] = labels[b];
        }
    }
}

// ---- GEMM + fused CE: BM=32 rows x all 512 classes; A fp32 direct w/ in-reg cvt ----
__global__ __launch_bounds__(256) void gemm_ce(
        const float* __restrict__ concepts, const unsigned short* __restrict__ Wb,
        const float* __restrict__ bias, const int* __restrict__ counts,
        const int* __restrict__ offsets, const int* __restrict__ order_rows,
        const int* __restrict__ lab_g, float* __restrict__ ce_sums) {
    int s = blockIdx.y;
    int cnt = counts[s];
    int row0 = blockIdx.x * BM;
    if (row0 >= cnt) return;
    int nrows = min(BM, cnt - row0);
    int base = offsets[s];

    int tid = threadIdx.x;
    int wave = tid >> 6, lane = tid & 63;
    int col = lane & 15, quad = lane >> 4;
    int c0 = wave * 128;

    f32x4 acc[2][8];
    f32x4 zf = {0.f, 0.f, 0.f, 0.f};
#pragma unroll
    for (int m = 0; m < 2; ++m)
#pragma unroll
        for (int t = 0; t < 8; ++t) acc[m][t] = zf;

    // A row pointers into concepts (fp32); invalid rows clamp to a valid row (discarded later)
    const float* aptr[2];
#pragma unroll
    for (int m = 0; m < 2; ++m) {
        int lr = min(m * 16 + col, nrows - 1);
        int orow = order_rows[base + row0 + lr];
        aptr[m] = concepts + (size_t)orow * D_N + quad * 8;
    }
    const unsigned short* bptr = Wb + ((size_t)s * C_N + c0 + col) * D_N + quad * 8;

    for (int k = 0; k < D_N; k += 32) {
        bf16x8 af[2];
#pragma unroll
        for (int m = 0; m < 2; ++m) {
            f32x4v x0 = *(const f32x4v*)(aptr[m] + k);
            f32x4v x1 = *(const f32x4v*)(aptr[m] + k + 4);
            af[m] = cvt8(x0, x1);
        }
        bf16x8 bfr[8];
#pragma unroll
        for (int t = 0; t < 8; ++t)
            bfr[t] = load_bf8(bptr + (size_t)t * 16 * D_N + k);
#pragma unroll
        for (int m = 0; m < 2; ++m)
#pragma unroll
            for (int t = 0; t < 8; ++t)
                acc[m][t] = __builtin_amdgcn_mfma_f32_16x16x32_bf16(af[m], bfr[t], acc[m][t], 0, 0, 0);
    }

    // epilogue: bias + per-row logsumexp + label logit + CE
    __shared__ float smax[4][BM];
    __shared__ float ssum[4][BM];
    __shared__ float gmax[BM];
    __shared__ float slab[BM];

#pragma unroll
    for (int t = 0; t < 8; ++t) {
        float bv = bias[(size_t)s * C_N + c0 + t * 16 + col];
#pragma unroll
        for (int m = 0; m < 2; ++m)
#pragma unroll
            for (int r = 0; r < 4; ++r) acc[m][t][r] += bv;
    }

    // per-wave row max over its 128 classes
#pragma unroll
    for (int m = 0; m < 2; ++m)
#pragma unroll
        for (int r = 0; r < 4; ++r) {
            float v = acc[m][0][r];
#pragma unroll
            for (int t = 1; t < 8; ++t) v = fmaxf(v, acc[m][t][r]);
            v = fmaxf(v, __shfl_xor(v, 1, 64));
            v = fmaxf(v, __shfl_xor(v, 2, 64));
            v = fmaxf(v, __shfl_xor(v, 4, 64));
            v = fmaxf(v, __shfl_xor(v, 8, 64));
            if (col == 0) smax[wave][m * 16 + quad * 4 + r] = v;
        }
    __syncthreads();
    if (tid < BM)
        gmax[tid] = fmaxf(fmaxf(smax[0][tid], smax[1][tid]),
                          fmaxf(smax[2][tid], smax[3][tid]));
    __syncthreads();

    // per-wave sum(exp) + label-logit capture
#pragma unroll
    for (int m = 0; m < 2; ++m)
#pragma unroll
        for (int r = 0; r < 4; ++r) {
            int row = m * 16 + quad * 4 + r;
            float gm = gmax[row];
            int lab = (row < nrows) ? lab_g[base + row0 + row] : -1;
            float sv = 0.f;
#pragma unroll
            for (int t = 0; t < 8; ++t) {
                float x = acc[m][t][r];
                sv += __expf(x - gm);
                if (c0 + t * 16 + col == lab) slab[row] = x;
            }
            sv += __shfl_xor(sv, 1, 64);
            sv += __shfl_xor(sv, 2, 64);
            sv += __shfl_xor(sv, 4, 64);
            sv += __shfl_xor(sv, 8, 64);
            if (col == 0) ssum[wave][row] = sv;
        }
    __syncthreads();

    if (wave == 0) {
        float ce = 0.f;
        if (lane < nrows) {
            float gs = ssum[0][lane] + ssum[1][lane] + ssum[2][lane] + ssum[3][lane];
            ce = gmax[lane] + __logf(gs) - slab[lane];
        }
        ce += __shfl_xor(ce, 1, 64);
        ce += __shfl_xor(ce, 2, 64);
        ce += __shfl_xor(ce, 4, 64);
        ce += __shfl_xor(ce, 8, 64);
        ce += __shfl_xor(ce, 16, 64);
        ce += __shfl_xor(ce, 32, 64);
        if (lane == 0) atomicAdd(&ce_sums[s], ce);
    }
}

__global__ void finalize(const int* __restrict__ counts, const float* __restrict__ ce_sums,
                         float* __restrict__ out) {
    if (threadIdx.x == 0 && blockIdx.x == 0) {
        float tot = 0.f; int np = 0;
        for (int s = 0; s < K_N; ++s) {
            int c = counts[s];
            if (c > 0) { tot += ce_sums[s] / (float)c; np++; }
        }
        out[0] = tot / (float)(np > 0 ? np : 1);
    }
}

extern "C" void kernel_launch(void* const* d_in, const int* in_sizes, int n_in,
                              void* d_out, int out_size, void* d_ws, size_t ws_size,
                              hipStream_t stream) {
    const float* concepts = (const float*)d_in[0];
    const int*   slot_ids = (const int*)d_in[1];
    const int*   labels   = (const int*)d_in[2];
    const float* W        = (const float*)d_in[3];
    const float* bias     = (const float*)d_in[4];
    float* out = (float*)d_out;

    char* ws = (char*)d_ws;
    int*   counts     = (int*)(ws + 0);
    int*   offsets    = (int*)(ws + 64);
    int*   cursors    = (int*)(ws + 128);
    float* ce_sums    = (float*)(ws + 192);
    int*   order_rows = (int*)(ws + 256);
    int*   lab_g      = (int*)(ws + 256 + 4 * B_N);
    unsigned short* Wb = (unsigned short*)(ws + 131072);
    // total ws use: 128 KiB + 16 MiB

    histk<<<1, 1024, 0, stream>>>(slot_ids, counts, offsets, cursors, ce_sums);
    prep<<<CONVW_BLOCKS + SCATTER_BLOCKS, 256, 0, stream>>>(W, Wb, slot_ids, labels,
                                                            cursors, order_rows, lab_g);
    gemm_ce<<<dim3(B_N / BM, K_N), 256, 0, stream>>>(concepts, Wb, bias, counts, offsets,
                                                     order_rows, lab_g, ce_sums);
    finalize<<<1, 1, 0, stream>>>(counts, ce_sums, out);
}